// Round 18
// baseline (248.245 us; speedup 1.0000x reference)
//
#include <hip/hip_runtime.h>

// RETAIN forward. B=128 T=64 C=8000 H=256 D=16 G=768. fp32 in/out;
// bf16 everywhere between embed and the heads (converted ONCE upstream).

typedef __attribute__((ext_vector_type(4))) float f32x4;
typedef __attribute__((ext_vector_type(8))) short short8;

__device__ inline short f2bf(float f) {
  unsigned u = __float_as_uint(f);
  u += 0x7fffu + ((u >> 16) & 1u);
  return (short)(u >> 16);
}
__device__ inline float bf2f(short u) {
  return __uint_as_float(((unsigned)(unsigned short)u) << 16);
}
__device__ inline float sigf(float x) { return 1.f / (1.f + __expf(-x)); }
__device__ inline float tanh_fast(float x) {
  x = fminf(fmaxf(x, -15.f), 15.f);
  float e = __expf(2.f * x);
  return (e - 1.f) / (e + 1.f);
}

// ---------------- prep (fused): transpose embed_W + pad W1s + pack W_hh + bf16 converts ----
__global__ __launch_bounds__(256) void prep(const float* __restrict__ embW,
                                            float* __restrict__ Wt,
                                            const float* __restrict__ w1,
                                            const float* __restrict__ w1d,
                                            float* __restrict__ o1,
                                            float* __restrict__ o2,
                                            const float* __restrict__ aWhh,
                                            const float* __restrict__ bWhh,
                                            short* __restrict__ wbf,
                                            const float* __restrict__ aWih,
                                            const float* __restrict__ bWih,
                                            const float* __restrict__ attnBW,
                                            short* __restrict__ wih16a,
                                            short* __restrict__ wih16b,
                                            short* __restrict__ attnBW16) {
  __shared__ float tile[32][33];
  const int bid = blockIdx.x;
  const int tid = threadIdx.x;
  if (bid < 2000) {
    const int c0 = (bid % 250) * 32, h0 = (bid / 250) * 32;
    const int tx = tid & 31, ty = tid >> 5;  // ty 0..7
#pragma unroll
    for (int k = 0; k < 4; ++k)
      tile[ty * 4 + k][tx] = embW[(long)(h0 + ty * 4 + k) * 8000 + c0 + tx];
    __syncthreads();
#pragma unroll
    for (int k = 0; k < 4; ++k)
      Wt[(long)(c0 + ty * 4 + k) * 256 + h0 + tx] = tile[tx][ty * 4 + k];
  } else if (bid < 2576) {
    const int idx = (bid - 2000) * 256 + tid;
    const int half = idx / (256 * 288);
    const int r = idx % (256 * 288);
    const int n = r / 288, k = r % 288;
    float v = (k < 272) ? (half ? w1d[n * 272 + k] : w1[n * 272 + k]) : 0.f;
    if (half) o2[r] = v; else o1[r] = v;
  } else if (bid < 2768) {
    const int F = (bid - 2576) * 256 + tid;  // 0..49151
    int f = F;
    const int lane = f & 63; f >>= 6;
    const int w = f & 15; f >>= 4;
    const int e = f % 3; f /= 3;
    const int kt = f & 7; f >>= 3;
    const int gru = f;
    const float* W = gru ? bWhh : aWhh;
    const int g = e * 256 + w * 16 + (lane & 15);
    const int k = kt * 32 + (lane >> 4) * 8;
    const float* p = W + (long)g * 256 + k;
    short8 v;
#pragma unroll
    for (int j = 0; j < 8; ++j) v[j] = f2bf(p[j]);
    *(short8*)(wbf + (long)F * 8) = v;
  } else {
    const int i = (bid - 2768) * 256 + tid;  // 0..458751
    if (i < 196608) wih16a[i] = f2bf(aWih[i]);
    else if (i < 393216) wih16b[i - 196608] = f2bf(bWih[i - 196608]);
    else attnBW16[i - 393216] = f2bf(attnBW[i - 393216]);
  }
}

// ---------------- sparse embed -> bf16, ballot-compacted nonzero list ----------------
__global__ __launch_bounds__(256) void embed_sparse(const float* __restrict__ x,
                                                    const float* __restrict__ Wt,
                                                    const float* __restrict__ eb,
                                                    short* __restrict__ emb16) {
  __shared__ int sidx[512];
  __shared__ float sval[512];
  __shared__ int scnt;
  const int bt = blockIdx.x;  // 0..8191
  const int tid = threadIdx.x;
  const int lane = tid & 63;
  if (tid == 0) scnt = 0;
  __syncthreads();
  const float* xr = x + (long)bt * 8000;
  for (int i = tid; i < 2000; i += 256) {
    float4 v = ((const float4*)xr)[i];
#pragma unroll
    for (int c = 0; c < 4; ++c) {
      const float val = (c == 0) ? v.x : (c == 1) ? v.y : (c == 2) ? v.z : v.w;
      const unsigned long long m = __ballot(val != 0.f);
      if (m) {
        const int leader = __ffsll((long long)m) - 1;
        int base = 0;
        if (lane == leader) base = atomicAdd(&scnt, __popcll(m));
        base = __shfl(base, leader);
        if (val != 0.f) {
          const int p = base + __popcll(m & ((1ull << lane) - 1ull));
          if (p < 512) { sidx[p] = i * 4 + c; sval[p] = val; }
        }
      }
    }
  }
  __syncthreads();
  const int n = min(scnt, 512);
  float acc = eb[tid];
  int i = 0;
  for (; i + 3 < n; i += 4) {  // 4 independent Wt row-loads in flight
    const float s0 = sval[i],     s1 = sval[i + 1];
    const float s2 = sval[i + 2], s3 = sval[i + 3];
    const float w0 = Wt[(long)sidx[i] * 256 + tid];
    const float w1 = Wt[(long)sidx[i + 1] * 256 + tid];
    const float w2 = Wt[(long)sidx[i + 2] * 256 + tid];
    const float w3 = Wt[(long)sidx[i + 3] * 256 + tid];
    acc += s0 * w0 + s1 * w1 + s2 * w2 + s3 * w3;
  }
  for (; i < n; ++i) acc += sval[i] * Wt[(long)sidx[i] * 256 + tid];
  emb16[(long)bt * 256 + tid] = f2bf(acc);
}

// ---------------- generic fp32 GEMM (logits): C = act(A @ B^T + bias) ----------------
__global__ __launch_bounds__(256) void gemm_bt(const float* __restrict__ A,
                                               const float* __restrict__ B,
                                               const float* __restrict__ bias,
                                               float* __restrict__ C,
                                               int M, int N, int K, int ldc, int act) {
  __shared__ short As[64][40];
  __shared__ short Bs[64][40];
  const int tid = threadIdx.x;
  const int lane = tid & 63, wave = tid >> 6;
  const int wm = wave >> 1, wn = wave & 1;
  const int l15 = lane & 15, lhi = lane >> 4;
  const int m0 = blockIdx.y * 64, n0 = blockIdx.x * 64;
  const int srow = tid >> 2, scol = (tid & 3) * 8;
  f32x4 acc[2][2];
#pragma unroll
  for (int i = 0; i < 2; ++i)
#pragma unroll
    for (int j = 0; j < 2; ++j) acc[i][j] = (f32x4){0.f, 0.f, 0.f, 0.f};

  for (int k0 = 0; k0 < K; k0 += 32) {
    __syncthreads();
    {
      const float* p = A + (long)(m0 + srow) * K + k0 + scol;
      float4 f0 = *(const float4*)p;
      float4 f1 = *(const float4*)(p + 4);
      short8 v;
      v[0] = f2bf(f0.x); v[1] = f2bf(f0.y); v[2] = f2bf(f0.z); v[3] = f2bf(f0.w);
      v[4] = f2bf(f1.x); v[5] = f2bf(f1.y); v[6] = f2bf(f1.z); v[7] = f2bf(f1.w);
      *(short8*)&As[srow][scol] = v;
      const float* q = B + (long)(n0 + srow) * K + k0 + scol;
      float4 g0 = *(const float4*)q;
      float4 g1 = *(const float4*)(q + 4);
      short8 u;
      u[0] = f2bf(g0.x); u[1] = f2bf(g0.y); u[2] = f2bf(g0.z); u[3] = f2bf(g0.w);
      u[4] = f2bf(g1.x); u[5] = f2bf(g1.y); u[6] = f2bf(g1.z); u[7] = f2bf(g1.w);
      *(short8*)&Bs[srow][scol] = u;
    }
    __syncthreads();
    short8 af0 = *(const short8*)&As[wm * 32 + l15][lhi * 8];
    short8 af1 = *(const short8*)&As[wm * 32 + 16 + l15][lhi * 8];
    short8 bf0 = *(const short8*)&Bs[wn * 32 + l15][lhi * 8];
    short8 bf1 = *(const short8*)&Bs[wn * 32 + 16 + l15][lhi * 8];
    acc[0][0] = __builtin_amdgcn_mfma_f32_16x16x32_bf16(af0, bf0, acc[0][0], 0, 0, 0);
    acc[0][1] = __builtin_amdgcn_mfma_f32_16x16x32_bf16(af0, bf1, acc[0][1], 0, 0, 0);
    acc[1][0] = __builtin_amdgcn_mfma_f32_16x16x32_bf16(af1, bf0, acc[1][0], 0, 0, 0);
    acc[1][1] = __builtin_amdgcn_mfma_f32_16x16x32_bf16(af1, bf1, acc[1][1], 0, 0, 0);
  }
#pragma unroll
  for (int j = 0; j < 2; ++j) {
    const int col = n0 + wn * 32 + j * 16 + l15;
    const float bv = bias[col];
#pragma unroll
    for (int i = 0; i < 2; ++i) {
#pragma unroll
      for (int r = 0; r < 4; ++r) {
        const int row = m0 + wm * 32 + i * 16 + lhi * 4 + r;
        float v = acc[i][j][r] + bv;
        if (act == 1) v = fmaxf(v, 0.f);
        else if (act == 2) v = tanh_fast(v);
        C[(long)row * ldc + col] = v;
      }
    }
  }
}

// ---------------- fused heads GEMM: z=0 -> h1(cls), z=1 -> h2(dl); relu ----------------
__global__ __launch_bounds__(256) void gemm_heads(const float* __restrict__ A,
                                                  const float* __restrict__ B0,
                                                  const float* __restrict__ B1,
                                                  const float* __restrict__ bias0,
                                                  const float* __restrict__ bias1,
                                                  float* __restrict__ C0,
                                                  float* __restrict__ C1) {
  const int z = blockIdx.z;
  const float* B = z ? B1 : B0;
  const float* bias = z ? bias1 : bias0;
  float* C = z ? C1 : C0;
  const int K = 288, ldc = 256;
  __shared__ short As[64][40];
  __shared__ short Bs[64][40];
  const int tid = threadIdx.x;
  const int lane = tid & 63, wave = tid >> 6;
  const int wm = wave >> 1, wn = wave & 1;
  const int l15 = lane & 15, lhi = lane >> 4;
  const int m0 = blockIdx.y * 64, n0 = blockIdx.x * 64;
  const int srow = tid >> 2, scol = (tid & 3) * 8;
  f32x4 acc[2][2];
#pragma unroll
  for (int i = 0; i < 2; ++i)
#pragma unroll
    for (int j = 0; j < 2; ++j) acc[i][j] = (f32x4){0.f, 0.f, 0.f, 0.f};

  for (int k0 = 0; k0 < K; k0 += 32) {
    __syncthreads();
    {
      const float* p = A + (long)(m0 + srow) * K + k0 + scol;
      float4 f0 = *(const float4*)p;
      float4 f1 = *(const float4*)(p + 4);
      short8 v;
      v[0] = f2bf(f0.x); v[1] = f2bf(f0.y); v[2] = f2bf(f0.z); v[3] = f2bf(f0.w);
      v[4] = f2bf(f1.x); v[5] = f2bf(f1.y); v[6] = f2bf(f1.z); v[7] = f2bf(f1.w);
      *(short8*)&As[srow][scol] = v;
      const float* q = B + (long)(n0 + srow) * K + k0 + scol;
      float4 g0 = *(const float4*)q;
      float4 g1 = *(const float4*)(q + 4);
      short8 u;
      u[0] = f2bf(g0.x); u[1] = f2bf(g0.y); u[2] = f2bf(g0.z); u[3] = f2bf(g0.w);
      u[4] = f2bf(g1.x); u[5] = f2bf(g1.y); u[6] = f2bf(g1.z); u[7] = f2bf(g1.w);
      *(short8*)&Bs[srow][scol] = u;
    }
    __syncthreads();
    short8 af0 = *(const short8*)&As[wm * 32 + l15][lhi * 8];
    short8 af1 = *(const short8*)&As[wm * 32 + 16 + l15][lhi * 8];
    short8 bf0 = *(const short8*)&Bs[wn * 32 + l15][lhi * 8];
    short8 bf1 = *(const short8*)&Bs[wn * 32 + 16 + l15][lhi * 8];
    acc[0][0] = __builtin_amdgcn_mfma_f32_16x16x32_bf16(af0, bf0, acc[0][0], 0, 0, 0);
    acc[0][1] = __builtin_amdgcn_mfma_f32_16x16x32_bf16(af0, bf1, acc[0][1], 0, 0, 0);
    acc[1][0] = __builtin_amdgcn_mfma_f32_16x16x32_bf16(af1, bf0, acc[1][0], 0, 0, 0);
    acc[1][1] = __builtin_amdgcn_mfma_f32_16x16x32_bf16(af1, bf1, acc[1][1], 0, 0, 0);
  }
#pragma unroll
  for (int j = 0; j < 2; ++j) {
    const int col = n0 + wn * 32 + j * 16 + l15;
    const float bv = bias[col];
#pragma unroll
    for (int i = 0; i < 2; ++i) {
#pragma unroll
      for (int r = 0; r < 4; ++r) {
        const int row = m0 + wm * 32 + i * 16 + lhi * 4 + r;
        C[(long)row * ldc + col] = fmaxf(acc[i][j][r] + bv, 0.f);
      }
    }
  }
}

// ---------------- dual-B GEMM, ALL-bf16 inputs -> bf16 outs (xp projections) ----------------
__global__ __launch_bounds__(256) void gemm_dual16(const short* __restrict__ A,
                                                   const short* __restrict__ B1,
                                                   const short* __restrict__ B2,
                                                   const float* __restrict__ bias1,
                                                   const float* __restrict__ bias2,
                                                   short* __restrict__ C1,
                                                   short* __restrict__ C2,
                                                   int K) {
  __shared__ short As[64][40];
  __shared__ short Bs1[64][40];
  __shared__ short Bs2[64][40];
  const int tid = threadIdx.x;
  const int lane = tid & 63, wave = tid >> 6;
  const int wm = wave >> 1, wn = wave & 1;
  const int l15 = lane & 15, lhi = lane >> 4;
  const int m0 = blockIdx.y * 64, n0 = blockIdx.x * 64;
  const int srow = tid >> 2, scol = (tid & 3) * 8;
  f32x4 acc1[2][2], acc2[2][2];
#pragma unroll
  for (int i = 0; i < 2; ++i)
#pragma unroll
    for (int j = 0; j < 2; ++j) {
      acc1[i][j] = (f32x4){0.f, 0.f, 0.f, 0.f};
      acc2[i][j] = (f32x4){0.f, 0.f, 0.f, 0.f};
    }

  for (int k0 = 0; k0 < K; k0 += 32) {
    __syncthreads();
    {
      *(short8*)&As[srow][scol]  = *(const short8*)(A  + (long)(m0 + srow) * K + k0 + scol);
      *(short8*)&Bs1[srow][scol] = *(const short8*)(B1 + (long)(n0 + srow) * K + k0 + scol);
      *(short8*)&Bs2[srow][scol] = *(const short8*)(B2 + (long)(n0 + srow) * K + k0 + scol);
    }
    __syncthreads();
    short8 af0 = *(const short8*)&As[wm * 32 + l15][lhi * 8];
    short8 af1 = *(const short8*)&As[wm * 32 + 16 + l15][lhi * 8];
    short8 b10 = *(const short8*)&Bs1[wn * 32 + l15][lhi * 8];
    short8 b11 = *(const short8*)&Bs1[wn * 32 + 16 + l15][lhi * 8];
    short8 b20 = *(const short8*)&Bs2[wn * 32 + l15][lhi * 8];
    short8 b21 = *(const short8*)&Bs2[wn * 32 + 16 + l15][lhi * 8];
    acc1[0][0] = __builtin_amdgcn_mfma_f32_16x16x32_bf16(af0, b10, acc1[0][0], 0, 0, 0);
    acc1[0][1] = __builtin_amdgcn_mfma_f32_16x16x32_bf16(af0, b11, acc1[0][1], 0, 0, 0);
    acc1[1][0] = __builtin_amdgcn_mfma_f32_16x16x32_bf16(af1, b10, acc1[1][0], 0, 0, 0);
    acc1[1][1] = __builtin_amdgcn_mfma_f32_16x16x32_bf16(af1, b11, acc1[1][1], 0, 0, 0);
    acc2[0][0] = __builtin_amdgcn_mfma_f32_16x16x32_bf16(af0, b20, acc2[0][0], 0, 0, 0);
    acc2[0][1] = __builtin_amdgcn_mfma_f32_16x16x32_bf16(af0, b21, acc2[0][1], 0, 0, 0);
    acc2[1][0] = __builtin_amdgcn_mfma_f32_16x16x32_bf16(af1, b20, acc2[1][0], 0, 0, 0);
    acc2[1][1] = __builtin_amdgcn_mfma_f32_16x16x32_bf16(af1, b21, acc2[1][1], 0, 0, 0);
  }
#pragma unroll
  for (int j = 0; j < 2; ++j) {
    const int col = n0 + wn * 32 + j * 16 + l15;
    const float bv1 = bias1[col];
    const float bv2 = bias2[col];
#pragma unroll
    for (int i = 0; i < 2; ++i) {
#pragma unroll
      for (int r = 0; r < 4; ++r) {
        const int row = m0 + wm * 32 + i * 16 + lhi * 4 + r;
        C1[(long)row * 768 + col] = f2bf(acc1[i][j][r] + bv1);
        C2[(long)row * 768 + col] = f2bf(acc2[i][j][r] + bv2);
      }
    }
  }
}

// ---------------- bf16-in GEMM (beta): C_bf16 = tanh(A16 @ B16^T + bias) ----------------
__global__ __launch_bounds__(256) void gemm16_bt(const short* __restrict__ A,
                                                 const short* __restrict__ B,
                                                 const float* __restrict__ bias,
                                                 short* __restrict__ C,
                                                 int K, int ldc) {
  __shared__ short As[64][40];
  __shared__ short Bs[64][40];
  const int tid = threadIdx.x;
  const int lane = tid & 63, wave = tid >> 6;
  const int wm = wave >> 1, wn = wave & 1;
  const int l15 = lane & 15, lhi = lane >> 4;
  const int m0 = blockIdx.y * 64, n0 = blockIdx.x * 64;
  const int srow = tid >> 2, scol = (tid & 3) * 8;
  f32x4 acc[2][2];
#pragma unroll
  for (int i = 0; i < 2; ++i)
#pragma unroll
    for (int j = 0; j < 2; ++j) acc[i][j] = (f32x4){0.f, 0.f, 0.f, 0.f};

  for (int k0 = 0; k0 < K; k0 += 32) {
    __syncthreads();
    {
      *(short8*)&As[srow][scol] = *(const short8*)(A + (long)(m0 + srow) * K + k0 + scol);
      *(short8*)&Bs[srow][scol] = *(const short8*)(B + (long)(n0 + srow) * K + k0 + scol);
    }
    __syncthreads();
    short8 af0 = *(const short8*)&As[wm * 32 + l15][lhi * 8];
    short8 af1 = *(const short8*)&As[wm * 32 + 16 + l15][lhi * 8];
    short8 bf0 = *(const short8*)&Bs[wn * 32 + l15][lhi * 8];
    short8 bf1 = *(const short8*)&Bs[wn * 32 + 16 + l15][lhi * 8];
    acc[0][0] = __builtin_amdgcn_mfma_f32_16x16x32_bf16(af0, bf0, acc[0][0], 0, 0, 0);
    acc[0][1] = __builtin_amdgcn_mfma_f32_16x16x32_bf16(af0, bf1, acc[0][1], 0, 0, 0);
    acc[1][0] = __builtin_amdgcn_mfma_f32_16x16x32_bf16(af1, bf0, acc[1][0], 0, 0, 0);
    acc[1][1] = __builtin_amdgcn_mfma_f32_16x16x32_bf16(af1, bf1, acc[1][1], 0, 0, 0);
  }
#pragma unroll
  for (int j = 0; j < 2; ++j) {
    const int col = n0 + wn * 32 + j * 16 + l15;
    const float bv = bias[col];
#pragma unroll
    for (int i = 0; i < 2; ++i) {
#pragma unroll
      for (int r = 0; r < 4; ++r) {
        const int row = m0 + wm * 32 + i * 16 + lhi * 4 + r;
        C[(long)row * ldc + col] = f2bf(tanh_fast(acc[i][j][r] + bv));
      }
    }
  }
}

// ---------------- GRU scan v17 (unchanged from R17, passing @242) ----------------
__global__ __launch_bounds__(1024, 4)
void gru_scan(const short* __restrict__ xpa,
              const short* __restrict__ xpb,
              const short* __restrict__ wbf,
              const float* __restrict__ abhh,
              const float* __restrict__ bbhh,
              short* __restrict__ aout,
              short* __restrict__ bout) {
  const int tid = threadIdx.x;
  const int lane = tid & 63, w = tid >> 6;   // wave 0..15
  const int l15 = lane & 15, lhi = lane >> 4;
  const int gru = blockIdx.x >> 5, chunk = blockIdx.x & 31;
  const int b0 = chunk * 4;
  const short* xp  = gru ? xpb : xpa;
  const float* bhh = gru ? bbhh : abhh;
  short* outp = gru ? bout : aout;

  __shared__ short hl[2][16][264];         // 16.9 KB double-buffered h (rows 4b real)
  __shared__ short wlds[2][16][3][64][8];  // 96 KB: kt 6,7 fragments

  auto FR = [&](int kt, int e) -> const short8* {
    return (const short8*)(wbf + ((((long)gru * 8 + kt) * 3 + e) * 16 + w) * 512 + (long)lane * 8);
  };

  // kt 0..4 -> registers (60 AGPR half)
  short8 wf[3][5];
#pragma unroll
  for (int e = 0; e < 3; ++e)
#pragma unroll
    for (int kt = 0; kt < 5; ++kt) wf[e][kt] = *FR(kt, e);
  // kt 6,7 -> LDS
#pragma unroll
  for (int e = 0; e < 3; ++e)
#pragma unroll
    for (int kt = 6; kt < 8; ++kt) *(short8*)&wlds[kt - 6][w][e][lane][0] = *FR(kt, e);

  float bh[3];
#pragma unroll
  for (int e = 0; e < 3; ++e) bh[e] = bhh[e * 256 + w * 16 + l15];

  for (int i = tid; i < 2 * 16 * 264; i += 1024) (&hl[0][0][0])[i] = 0;

  const int col = w * 16 + l15;
  const short* xpl = xp + ((long)(b0 + lhi) * 64) * 768 + col;

  float hreg = 0.f;
  short xc0 = xpl[0], xc1 = xpl[256], xc2 = xpl[512];  // prefetch xp[t=0]
  __syncthreads();  // weights/hl visible (full drain, once)

  for (int t = 0; t < 64; ++t) {
    const int cur = t & 1;
    const short* xpn = xpl + (long)(t + 1 < 64 ? t + 1 : 63) * 768;
    short xn0 = xpn[0], xn1 = xpn[256], xn2 = xpn[512];
    short8 s50 = *FR(5, 0), s51 = *FR(5, 1), s52 = *FR(5, 2);

    f32x4 acc[3];
#pragma unroll
    for (int e = 0; e < 3; ++e) acc[e] = (f32x4){0.f, 0.f, 0.f, 0.f};
#pragma unroll
    for (int kt = 0; kt < 5; ++kt) {
      short8 a = *(const short8*)&hl[cur][l15][kt * 32 + lhi * 8];
      acc[0] = __builtin_amdgcn_mfma_f32_16x16x32_bf16(a, wf[0][kt], acc[0], 0, 0, 0);
      acc[1] = __builtin_amdgcn_mfma_f32_16x16x32_bf16(a, wf[1][kt], acc[1], 0, 0, 0);
      acc[2] = __builtin_amdgcn_mfma_f32_16x16x32_bf16(a, wf[2][kt], acc[2], 0, 0, 0);
    }
    {
      short8 a = *(const short8*)&hl[cur][l15][5 * 32 + lhi * 8];
      acc[0] = __builtin_amdgcn_mfma_f32_16x16x32_bf16(a, s50, acc[0], 0, 0, 0);
      acc[1] = __builtin_amdgcn_mfma_f32_16x16x32_bf16(a, s51, acc[1], 0, 0, 0);
      acc[2] = __builtin_amdgcn_mfma_f32_16x16x32_bf16(a, s52, acc[2], 0, 0, 0);
    }
#pragma unroll
    for (int kt = 6; kt < 8; ++kt) {
      short8 a = *(const short8*)&hl[cur][l15][kt * 32 + lhi * 8];
#pragma unroll
      for (int e = 0; e < 3; ++e) {
        short8 wl = *(const short8*)&wlds[kt - 6][w][e][lane][0];
        acc[e] = __builtin_amdgcn_mfma_f32_16x16x32_bf16(a, wl, acc[e], 0, 0, 0);
      }
    }

    {
      const float r = sigf(bf2f(xc0) + acc[0][0] + bh[0]);
      const float z = sigf(bf2f(xc1) + acc[1][0] + bh[1]);
      const float n = tanh_fast(bf2f(xc2) + r * (acc[2][0] + bh[2]));
      const float hn = (1.f - z) * n + z * hreg;
      hreg = hn;
      const short hb = f2bf(hn);
      hl[cur ^ 1][lhi << 2][col] = hb;
      outp[((long)(b0 + lhi) * 64 + t) * 256 + col] = hb;
    }
    xc0 = xn0; xc1 = xn1; xc2 = xn2;
    asm volatile("s_waitcnt lgkmcnt(0)" ::: "memory");
    __builtin_amdgcn_sched_barrier(0);
    __builtin_amdgcn_s_barrier();
    __builtin_amdgcn_sched_barrier(0);
  }
}

// ---------------- fused e_alpha softmax + context + combined (bf16 inputs) ----------------
__global__ __launch_bounds__(256) void alpha_ctx(const short* __restrict__ aout16,
                                                 const float* __restrict__ aW,
                                                 const float* __restrict__ ab,
                                                 const short* __restrict__ emb16,
                                                 const short* __restrict__ beta16,
                                                 const float* __restrict__ demo,
                                                 float* __restrict__ comb) {
  __shared__ float part[64][4];
  __shared__ float al[64];
  const int b = blockIdx.x, tid = threadIdx.x;
  const int t = tid >> 2, q = tid & 3;
  const short* p = aout16 + (long)(b * 64 + t) * 256 + q * 64;
  const float* wv = aW + q * 64;
  float s = 0.f;
  for (int i = 0; i < 64; ++i) s += bf2f(p[i]) * wv[i];
  part[t][q] = s;
  __syncthreads();
  if (tid < 64) {
    float e = part[tid][0] + part[tid][1] + part[tid][2] + part[tid][3] + ab[0];
    float m = e;
    for (int k = 32; k; k >>= 1) m = fmaxf(m, __shfl_xor(m, k));
    float ex = __expf(e - m);
    float sum = ex;
    for (int k = 32; k; k >>= 1) sum += __shfl_xor(sum, k);
    al[tid] = ex / sum;
  }
  __syncthreads();
  const int h = tid;
  float acc = 0.f;
  for (int t2 = 0; t2 < 64; ++t2) {
    const long ix = (long)(b * 64 + t2) * 256 + h;
    acc += al[t2] * bf2f(emb16[ix]) * bf2f(beta16[ix]);
  }
  comb[b * 288 + h] = acc;
  if (h < 16) comb[b * 288 + 256 + h] = demo[b * 16 + h];
  else if (h < 32) comb[b * 288 + 256 + h] = 0.f;
}

// ---------------- death/LOS head final dot ----------------
__global__ __launch_bounds__(64) void dl_head(const float* __restrict__ h2,
                                              const float* __restrict__ w,
                                              const float* __restrict__ bias,
                                              float* __restrict__ out) {
  const int b = blockIdx.x, lane = threadIdx.x;
  float s = 0.f;
#pragma unroll
  for (int i = 0; i < 4; ++i) s += h2[b * 256 + lane * 4 + i] * w[lane * 4 + i];
  for (int k = 32; k; k >>= 1) s += __shfl_xor(s, k);
  if (lane == 0) out[(long)b * 8001 + 8000] = s + bias[0];
}

extern "C" void kernel_launch(void* const* d_in, const int* in_sizes, int n_in,
                              void* d_out, int out_size, void* d_ws, size_t ws_size,
                              hipStream_t stream) {
  (void)in_sizes; (void)n_in; (void)out_size; (void)ws_size;
  const float* x      = (const float*)d_in[0];
  const float* demo   = (const float*)d_in[1];
  const float* embW   = (const float*)d_in[2];
  const float* embB   = (const float*)d_in[3];
  const float* aWih   = (const float*)d_in[4];
  const float* aWhh   = (const float*)d_in[5];
  const float* abih   = (const float*)d_in[6];
  const float* abhh   = (const float*)d_in[7];
  const float* bWih   = (const float*)d_in[8];
  const float* bWhh   = (const float*)d_in[9];
  const float* bbih   = (const float*)d_in[10];
  const float* bbhh   = (const float*)d_in[11];
  const float* attnAW = (const float*)d_in[12];
  const float* attnAb = (const float*)d_in[13];
  const float* attnBW = (const float*)d_in[14];
  const float* attnBb = (const float*)d_in[15];
  const float* clsW1  = (const float*)d_in[16];
  const float* clsb1  = (const float*)d_in[17];
  const float* clsW2  = (const float*)d_in[18];
  const float* clsb2  = (const float*)d_in[19];
  const float* dlW1   = (const float*)d_in[20];
  const float* dlb1   = (const float*)d_in[21];
  const float* dlW2   = (const float*)d_in[22];
  const float* dlb2   = (const float*)d_in[23];
  float* out = (float*)d_out;
  float* ws = (float*)d_ws;

  float* Wt      = ws;                        // 2,048,000 f
  short* emb16   = (short*)(Wt + 2048000);    // 2,097,152 s
  short* xpa16   = emb16 + 2097152;           // 6,291,456 s
  short* xpb16   = xpa16 + 6291456;           // 6,291,456 s
  short* aout16  = xpb16 + 6291456;           // 2,097,152 s
  short* bout16  = aout16 + 2097152;          // 2,097,152 s
  short* beta16  = bout16 + 2097152;          // 2,097,152 s
  float* comb    = (float*)(beta16 + 2097152); // 36,864 f
  float* h1      = comb + 36864;              // 32,768 f
  float* h2      = h1 + 32768;                // 32,768 f
  float* W1p     = h2 + 32768;                // 73,728 f
  float* W1pd    = W1p + 73728;               // 73,728 f
  short* wbf     = (short*)(W1pd + 73728);    // 393,216 s
  short* wih16a  = wbf + 393216;              // 196,608 s
  short* wih16b  = wih16a + 196608;           // 196,608 s
  short* attnBW16 = wih16b + 196608;          // 65,536 s

  prep<<<dim3(4560), dim3(256), 0, stream>>>(embW, Wt, clsW1, dlW1, W1p, W1pd,
                                             aWhh, bWhh, wbf, aWih, bWih, attnBW,
                                             wih16a, wih16b, attnBW16);
  embed_sparse<<<dim3(8192), dim3(256), 0, stream>>>(x, Wt, embB, emb16);
  gemm_dual16<<<dim3(12, 128), dim3(256), 0, stream>>>(emb16, wih16a, wih16b, abih, bbih,
                                                       xpa16, xpb16, 256);
  gru_scan<<<dim3(64), dim3(1024), 0, stream>>>(xpa16, xpb16, wbf, abhh, bbhh, aout16, bout16);
  gemm16_bt<<<dim3(4, 128), dim3(256), 0, stream>>>(bout16, attnBW16, attnBb, beta16, 256, 256);
  alpha_ctx<<<dim3(128), dim3(256), 0, stream>>>(aout16, attnAW, attnAb, emb16, beta16, demo, comb);
  gemm_heads<<<dim3(4, 2, 2), dim3(256), 0, stream>>>(comb, W1p, W1pd, clsb1, dlb1, h1, h2);
  gemm_bt<<<dim3(125, 2), dim3(256), 0, stream>>>(h1, clsW2, clsb2, out, 128, 8000, 256, 8001, 0);
  dl_head<<<dim3(128), dim3(64), 0, stream>>>(h2, dlW2, dlb2, out);
}

// Round 19
// 227.104 us; speedup vs baseline: 1.0931x; 1.0931x over previous
//
#include <hip/hip_runtime.h>

// RETAIN forward. B=128 T=64 C=8000 H=256 D=16 G=768. fp32 in/out;
// bf16 everywhere between embed and the heads (converted ONCE upstream).

typedef __attribute__((ext_vector_type(4))) float f32x4;
typedef __attribute__((ext_vector_type(8))) short short8;

__device__ inline short f2bf(float f) {
  unsigned u = __float_as_uint(f);
  u += 0x7fffu + ((u >> 16) & 1u);
  return (short)(u >> 16);
}
__device__ inline float bf2f(short u) {
  return __uint_as_float(((unsigned)(unsigned short)u) << 16);
}
__device__ inline float sigf(float x) { return 1.f / (1.f + __expf(-x)); }
__device__ inline float tanh_fast(float x) {
  x = fminf(fmaxf(x, -15.f), 15.f);
  float e = __expf(2.f * x);
  return (e - 1.f) / (e + 1.f);
}

// ---------------- prep (fused): transpose embed_W (->bf16) + pad W1s + pack W_hh + converts ----
// blocks 0..1999: transpose embed_W [256,8000] -> Wt16 [8000,256] bf16
// blocks 2000..2575: pad cls/dl W1
// blocks 2576..2767: pack W_hh frags
// blocks 2768..4559: bf16 convert concat(aWih,bWih,attnBW)
__global__ __launch_bounds__(256) void prep(const float* __restrict__ embW,
                                            short* __restrict__ Wt16,
                                            const float* __restrict__ w1,
                                            const float* __restrict__ w1d,
                                            float* __restrict__ o1,
                                            float* __restrict__ o2,
                                            const float* __restrict__ aWhh,
                                            const float* __restrict__ bWhh,
                                            short* __restrict__ wbf,
                                            const float* __restrict__ aWih,
                                            const float* __restrict__ bWih,
                                            const float* __restrict__ attnBW,
                                            short* __restrict__ wih16a,
                                            short* __restrict__ wih16b,
                                            short* __restrict__ attnBW16) {
  __shared__ float tile[32][33];
  const int bid = blockIdx.x;
  const int tid = threadIdx.x;
  if (bid < 2000) {
    const int c0 = (bid % 250) * 32, h0 = (bid / 250) * 32;
    const int tx = tid & 31, ty = tid >> 5;  // ty 0..7
#pragma unroll
    for (int k = 0; k < 4; ++k)
      tile[ty * 4 + k][tx] = embW[(long)(h0 + ty * 4 + k) * 8000 + c0 + tx];
    __syncthreads();
#pragma unroll
    for (int k = 0; k < 4; ++k)
      Wt16[(long)(c0 + ty * 4 + k) * 256 + h0 + tx] = f2bf(tile[tx][ty * 4 + k]);
  } else if (bid < 2576) {
    const int idx = (bid - 2000) * 256 + tid;
    const int half = idx / (256 * 288);
    const int r = idx % (256 * 288);
    const int n = r / 288, k = r % 288;
    float v = (k < 272) ? (half ? w1d[n * 272 + k] : w1[n * 272 + k]) : 0.f;
    if (half) o2[r] = v; else o1[r] = v;
  } else if (bid < 2768) {
    const int F = (bid - 2576) * 256 + tid;  // 0..49151
    int f = F;
    const int lane = f & 63; f >>= 6;
    const int w = f & 15; f >>= 4;
    const int e = f % 3; f /= 3;
    const int kt = f & 7; f >>= 3;
    const int gru = f;
    const float* W = gru ? bWhh : aWhh;
    const int g = e * 256 + w * 16 + (lane & 15);
    const int k = kt * 32 + (lane >> 4) * 8;
    const float* p = W + (long)g * 256 + k;
    short8 v;
#pragma unroll
    for (int j = 0; j < 8; ++j) v[j] = f2bf(p[j]);
    *(short8*)(wbf + (long)F * 8) = v;
  } else {
    const int i = (bid - 2768) * 256 + tid;  // 0..458751
    if (i < 196608) wih16a[i] = f2bf(aWih[i]);
    else if (i < 393216) wih16b[i - 196608] = f2bf(bWih[i - 196608]);
    else attnBW16[i - 393216] = f2bf(attnBW[i - 393216]);
  }
}

// ---------------- sparse embed -> bf16 (bf16 Wt gather, fp32 accum) ----------------
__global__ __launch_bounds__(256) void embed_sparse(const float* __restrict__ x,
                                                    const short* __restrict__ Wt16,
                                                    const float* __restrict__ eb,
                                                    short* __restrict__ emb16) {
  __shared__ int sidx[512];
  __shared__ float sval[512];
  __shared__ int scnt;
  const int bt = blockIdx.x;  // 0..8191
  const int tid = threadIdx.x;
  if (tid == 0) scnt = 0;
  __syncthreads();
  const float* xr = x + (long)bt * 8000;
  for (int i = tid; i < 2000; i += 256) {
    float4 v = ((const float4*)xr)[i];
    if (v.x != 0.f) { int p = atomicAdd(&scnt, 1); if (p < 512) { sidx[p] = i * 4 + 0; sval[p] = v.x; } }
    if (v.y != 0.f) { int p = atomicAdd(&scnt, 1); if (p < 512) { sidx[p] = i * 4 + 1; sval[p] = v.y; } }
    if (v.z != 0.f) { int p = atomicAdd(&scnt, 1); if (p < 512) { sidx[p] = i * 4 + 2; sval[p] = v.z; } }
    if (v.w != 0.f) { int p = atomicAdd(&scnt, 1); if (p < 512) { sidx[p] = i * 4 + 3; sval[p] = v.w; } }
  }
  __syncthreads();
  const int n = min(scnt, 512);
  float acc = eb[tid];
  for (int i = 0; i < n; ++i) acc += sval[i] * bf2f(Wt16[(long)sidx[i] * 256 + tid]);
  emb16[(long)bt * 256 + tid] = f2bf(acc);
}

// ---------------- generic fp32 GEMM (logits): C = act(A @ B^T + bias) ----------------
__global__ __launch_bounds__(256) void gemm_bt(const float* __restrict__ A,
                                               const float* __restrict__ B,
                                               const float* __restrict__ bias,
                                               float* __restrict__ C,
                                               int M, int N, int K, int ldc, int act) {
  __shared__ short As[64][40];
  __shared__ short Bs[64][40];
  const int tid = threadIdx.x;
  const int lane = tid & 63, wave = tid >> 6;
  const int wm = wave >> 1, wn = wave & 1;
  const int l15 = lane & 15, lhi = lane >> 4;
  const int m0 = blockIdx.y * 64, n0 = blockIdx.x * 64;
  const int srow = tid >> 2, scol = (tid & 3) * 8;
  f32x4 acc[2][2];
#pragma unroll
  for (int i = 0; i < 2; ++i)
#pragma unroll
    for (int j = 0; j < 2; ++j) acc[i][j] = (f32x4){0.f, 0.f, 0.f, 0.f};

  for (int k0 = 0; k0 < K; k0 += 32) {
    __syncthreads();
    {
      const float* p = A + (long)(m0 + srow) * K + k0 + scol;
      float4 f0 = *(const float4*)p;
      float4 f1 = *(const float4*)(p + 4);
      short8 v;
      v[0] = f2bf(f0.x); v[1] = f2bf(f0.y); v[2] = f2bf(f0.z); v[3] = f2bf(f0.w);
      v[4] = f2bf(f1.x); v[5] = f2bf(f1.y); v[6] = f2bf(f1.z); v[7] = f2bf(f1.w);
      *(short8*)&As[srow][scol] = v;
      const float* q = B + (long)(n0 + srow) * K + k0 + scol;
      float4 g0 = *(const float4*)q;
      float4 g1 = *(const float4*)(q + 4);
      short8 u;
      u[0] = f2bf(g0.x); u[1] = f2bf(g0.y); u[2] = f2bf(g0.z); u[3] = f2bf(g0.w);
      u[4] = f2bf(g1.x); u[5] = f2bf(g1.y); u[6] = f2bf(g1.z); u[7] = f2bf(g1.w);
      *(short8*)&Bs[srow][scol] = u;
    }
    __syncthreads();
    short8 af0 = *(const short8*)&As[wm * 32 + l15][lhi * 8];
    short8 af1 = *(const short8*)&As[wm * 32 + 16 + l15][lhi * 8];
    short8 bf0 = *(const short8*)&Bs[wn * 32 + l15][lhi * 8];
    short8 bf1 = *(const short8*)&Bs[wn * 32 + 16 + l15][lhi * 8];
    acc[0][0] = __builtin_amdgcn_mfma_f32_16x16x32_bf16(af0, bf0, acc[0][0], 0, 0, 0);
    acc[0][1] = __builtin_amdgcn_mfma_f32_16x16x32_bf16(af0, bf1, acc[0][1], 0, 0, 0);
    acc[1][0] = __builtin_amdgcn_mfma_f32_16x16x32_bf16(af1, bf0, acc[1][0], 0, 0, 0);
    acc[1][1] = __builtin_amdgcn_mfma_f32_16x16x32_bf16(af1, bf1, acc[1][1], 0, 0, 0);
  }
#pragma unroll
  for (int j = 0; j < 2; ++j) {
    const int col = n0 + wn * 32 + j * 16 + l15;
    const float bv = bias[col];
#pragma unroll
    for (int i = 0; i < 2; ++i) {
#pragma unroll
      for (int r = 0; r < 4; ++r) {
        const int row = m0 + wm * 32 + i * 16 + lhi * 4 + r;
        float v = acc[i][j][r] + bv;
        if (act == 1) v = fmaxf(v, 0.f);
        else if (act == 2) v = tanh_fast(v);
        C[(long)row * ldc + col] = v;
      }
    }
  }
}

// ---------------- fused heads GEMM: z=0 -> h1(cls), z=1 -> h2(dl); relu ----------------
__global__ __launch_bounds__(256) void gemm_heads(const float* __restrict__ A,
                                                  const float* __restrict__ B0,
                                                  const float* __restrict__ B1,
                                                  const float* __restrict__ bias0,
                                                  const float* __restrict__ bias1,
                                                  float* __restrict__ C0,
                                                  float* __restrict__ C1) {
  const int z = blockIdx.z;
  const float* B = z ? B1 : B0;
  const float* bias = z ? bias1 : bias0;
  float* C = z ? C1 : C0;
  const int K = 288, ldc = 256;
  __shared__ short As[64][40];
  __shared__ short Bs[64][40];
  const int tid = threadIdx.x;
  const int lane = tid & 63, wave = tid >> 6;
  const int wm = wave >> 1, wn = wave & 1;
  const int l15 = lane & 15, lhi = lane >> 4;
  const int m0 = blockIdx.y * 64, n0 = blockIdx.x * 64;
  const int srow = tid >> 2, scol = (tid & 3) * 8;
  f32x4 acc[2][2];
#pragma unroll
  for (int i = 0; i < 2; ++i)
#pragma unroll
    for (int j = 0; j < 2; ++j) acc[i][j] = (f32x4){0.f, 0.f, 0.f, 0.f};

  for (int k0 = 0; k0 < K; k0 += 32) {
    __syncthreads();
    {
      const float* p = A + (long)(m0 + srow) * K + k0 + scol;
      float4 f0 = *(const float4*)p;
      float4 f1 = *(const float4*)(p + 4);
      short8 v;
      v[0] = f2bf(f0.x); v[1] = f2bf(f0.y); v[2] = f2bf(f0.z); v[3] = f2bf(f0.w);
      v[4] = f2bf(f1.x); v[5] = f2bf(f1.y); v[6] = f2bf(f1.z); v[7] = f2bf(f1.w);
      *(short8*)&As[srow][scol] = v;
      const float* q = B + (long)(n0 + srow) * K + k0 + scol;
      float4 g0 = *(const float4*)q;
      float4 g1 = *(const float4*)(q + 4);
      short8 u;
      u[0] = f2bf(g0.x); u[1] = f2bf(g0.y); u[2] = f2bf(g0.z); u[3] = f2bf(g0.w);
      u[4] = f2bf(g1.x); u[5] = f2bf(g1.y); u[6] = f2bf(g1.z); u[7] = f2bf(g1.w);
      *(short8*)&Bs[srow][scol] = u;
    }
    __syncthreads();
    short8 af0 = *(const short8*)&As[wm * 32 + l15][lhi * 8];
    short8 af1 = *(const short8*)&As[wm * 32 + 16 + l15][lhi * 8];
    short8 bf0 = *(const short8*)&Bs[wn * 32 + l15][lhi * 8];
    short8 bf1 = *(const short8*)&Bs[wn * 32 + 16 + l15][lhi * 8];
    acc[0][0] = __builtin_amdgcn_mfma_f32_16x16x32_bf16(af0, bf0, acc[0][0], 0, 0, 0);
    acc[0][1] = __builtin_amdgcn_mfma_f32_16x16x32_bf16(af0, bf1, acc[0][1], 0, 0, 0);
    acc[1][0] = __builtin_amdgcn_mfma_f32_16x16x32_bf16(af1, bf0, acc[1][0], 0, 0, 0);
    acc[1][1] = __builtin_amdgcn_mfma_f32_16x16x32_bf16(af1, bf1, acc[1][1], 0, 0, 0);
  }
#pragma unroll
  for (int j = 0; j < 2; ++j) {
    const int col = n0 + wn * 32 + j * 16 + l15;
    const float bv = bias[col];
#pragma unroll
    for (int i = 0; i < 2; ++i) {
#pragma unroll
      for (int r = 0; r < 4; ++r) {
        const int row = m0 + wm * 32 + i * 16 + lhi * 4 + r;
        C[(long)row * ldc + col] = fmaxf(acc[i][j][r] + bv, 0.f);
      }
    }
  }
}

// ---------------- dual-B GEMM, ALL-bf16 inputs -> bf16 outs (xp projections) ----------------
__global__ __launch_bounds__(256) void gemm_dual16(const short* __restrict__ A,
                                                   const short* __restrict__ B1,
                                                   const short* __restrict__ B2,
                                                   const float* __restrict__ bias1,
                                                   const float* __restrict__ bias2,
                                                   short* __restrict__ C1,
                                                   short* __restrict__ C2,
                                                   int K) {
  __shared__ short As[64][40];
  __shared__ short Bs1[64][40];
  __shared__ short Bs2[64][40];
  const int tid = threadIdx.x;
  const int lane = tid & 63, wave = tid >> 6;
  const int wm = wave >> 1, wn = wave & 1;
  const int l15 = lane & 15, lhi = lane >> 4;
  const int m0 = blockIdx.y * 64, n0 = blockIdx.x * 64;
  const int srow = tid >> 2, scol = (tid & 3) * 8;
  f32x4 acc1[2][2], acc2[2][2];
#pragma unroll
  for (int i = 0; i < 2; ++i)
#pragma unroll
    for (int j = 0; j < 2; ++j) {
      acc1[i][j] = (f32x4){0.f, 0.f, 0.f, 0.f};
      acc2[i][j] = (f32x4){0.f, 0.f, 0.f, 0.f};
    }

  for (int k0 = 0; k0 < K; k0 += 32) {
    __syncthreads();
    {
      *(short8*)&As[srow][scol]  = *(const short8*)(A  + (long)(m0 + srow) * K + k0 + scol);
      *(short8*)&Bs1[srow][scol] = *(const short8*)(B1 + (long)(n0 + srow) * K + k0 + scol);
      *(short8*)&Bs2[srow][scol] = *(const short8*)(B2 + (long)(n0 + srow) * K + k0 + scol);
    }
    __syncthreads();
    short8 af0 = *(const short8*)&As[wm * 32 + l15][lhi * 8];
    short8 af1 = *(const short8*)&As[wm * 32 + 16 + l15][lhi * 8];
    short8 b10 = *(const short8*)&Bs1[wn * 32 + l15][lhi * 8];
    short8 b11 = *(const short8*)&Bs1[wn * 32 + 16 + l15][lhi * 8];
    short8 b20 = *(const short8*)&Bs2[wn * 32 + l15][lhi * 8];
    short8 b21 = *(const short8*)&Bs2[wn * 32 + 16 + l15][lhi * 8];
    acc1[0][0] = __builtin_amdgcn_mfma_f32_16x16x32_bf16(af0, b10, acc1[0][0], 0, 0, 0);
    acc1[0][1] = __builtin_amdgcn_mfma_f32_16x16x32_bf16(af0, b11, acc1[0][1], 0, 0, 0);
    acc1[1][0] = __builtin_amdgcn_mfma_f32_16x16x32_bf16(af1, b10, acc1[1][0], 0, 0, 0);
    acc1[1][1] = __builtin_amdgcn_mfma_f32_16x16x32_bf16(af1, b11, acc1[1][1], 0, 0, 0);
    acc2[0][0] = __builtin_amdgcn_mfma_f32_16x16x32_bf16(af0, b20, acc2[0][0], 0, 0, 0);
    acc2[0][1] = __builtin_amdgcn_mfma_f32_16x16x32_bf16(af0, b21, acc2[0][1], 0, 0, 0);
    acc2[1][0] = __builtin_amdgcn_mfma_f32_16x16x32_bf16(af1, b20, acc2[1][0], 0, 0, 0);
    acc2[1][1] = __builtin_amdgcn_mfma_f32_16x16x32_bf16(af1, b21, acc2[1][1], 0, 0, 0);
  }
#pragma unroll
  for (int j = 0; j < 2; ++j) {
    const int col = n0 + wn * 32 + j * 16 + l15;
    const float bv1 = bias1[col];
    const float bv2 = bias2[col];
#pragma unroll
    for (int i = 0; i < 2; ++i) {
#pragma unroll
      for (int r = 0; r < 4; ++r) {
        const int row = m0 + wm * 32 + i * 16 + lhi * 4 + r;
        C1[(long)row * 768 + col] = f2bf(acc1[i][j][r] + bv1);
        C2[(long)row * 768 + col] = f2bf(acc2[i][j][r] + bv2);
      }
    }
  }
}

// ---------------- bf16-in GEMM (beta): C_bf16 = tanh(A16 @ B16^T + bias) ----------------
__global__ __launch_bounds__(256) void gemm16_bt(const short* __restrict__ A,
                                                 const short* __restrict__ B,
                                                 const float* __restrict__ bias,
                                                 short* __restrict__ C,
                                                 int K, int ldc) {
  __shared__ short As[64][40];
  __shared__ short Bs[64][40];
  const int tid = threadIdx.x;
  const int lane = tid & 63, wave = tid >> 6;
  const int wm = wave >> 1, wn = wave & 1;
  const int l15 = lane & 15, lhi = lane >> 4;
  const int m0 = blockIdx.y * 64, n0 = blockIdx.x * 64;
  const int srow = tid >> 2, scol = (tid & 3) * 8;
  f32x4 acc[2][2];
#pragma unroll
  for (int i = 0; i < 2; ++i)
#pragma unroll
    for (int j = 0; j < 2; ++j) acc[i][j] = (f32x4){0.f, 0.f, 0.f, 0.f};

  for (int k0 = 0; k0 < K; k0 += 32) {
    __syncthreads();
    {
      *(short8*)&As[srow][scol] = *(const short8*)(A + (long)(m0 + srow) * K + k0 + scol);
      *(short8*)&Bs[srow][scol] = *(const short8*)(B + (long)(n0 + srow) * K + k0 + scol);
    }
    __syncthreads();
    short8 af0 = *(const short8*)&As[wm * 32 + l15][lhi * 8];
    short8 af1 = *(const short8*)&As[wm * 32 + 16 + l15][lhi * 8];
    short8 bf0 = *(const short8*)&Bs[wn * 32 + l15][lhi * 8];
    short8 bf1 = *(const short8*)&Bs[wn * 32 + 16 + l15][lhi * 8];
    acc[0][0] = __builtin_amdgcn_mfma_f32_16x16x32_bf16(af0, bf0, acc[0][0], 0, 0, 0);
    acc[0][1] = __builtin_amdgcn_mfma_f32_16x16x32_bf16(af0, bf1, acc[0][1], 0, 0, 0);
    acc[1][0] = __builtin_amdgcn_mfma_f32_16x16x32_bf16(af1, bf0, acc[1][0], 0, 0, 0);
    acc[1][1] = __builtin_amdgcn_mfma_f32_16x16x32_bf16(af1, bf1, acc[1][1], 0, 0, 0);
  }
#pragma unroll
  for (int j = 0; j < 2; ++j) {
    const int col = n0 + wn * 32 + j * 16 + l15;
    const float bv = bias[col];
#pragma unroll
    for (int i = 0; i < 2; ++i) {
#pragma unroll
      for (int r = 0; r < 4; ++r) {
        const int row = m0 + wm * 32 + i * 16 + lhi * 4 + r;
        C[(long)row * ldc + col] = f2bf(tanh_fast(acc[i][j][r] + bv));
      }
    }
  }
}

// ---------------- GRU scan v17 (unchanged, passing @242) ----------------
__global__ __launch_bounds__(1024, 4)
void gru_scan(const short* __restrict__ xpa,
              const short* __restrict__ xpb,
              const short* __restrict__ wbf,
              const float* __restrict__ abhh,
              const float* __restrict__ bbhh,
              short* __restrict__ aout,
              short* __restrict__ bout) {
  const int tid = threadIdx.x;
  const int lane = tid & 63, w = tid >> 6;   // wave 0..15
  const int l15 = lane & 15, lhi = lane >> 4;
  const int gru = blockIdx.x >> 5, chunk = blockIdx.x & 31;
  const int b0 = chunk * 4;
  const short* xp  = gru ? xpb : xpa;
  const float* bhh = gru ? bbhh : abhh;
  short* outp = gru ? bout : aout;

  __shared__ short hl[2][16][264];         // 16.9 KB double-buffered h (rows 4b real)
  __shared__ short wlds[2][16][3][64][8];  // 96 KB: kt 6,7 fragments

  auto FR = [&](int kt, int e) -> const short8* {
    return (const short8*)(wbf + ((((long)gru * 8 + kt) * 3 + e) * 16 + w) * 512 + (long)lane * 8);
  };

  // kt 0..4 -> registers (60 AGPR half)
  short8 wf[3][5];
#pragma unroll
  for (int e = 0; e < 3; ++e)
#pragma unroll
    for (int kt = 0; kt < 5; ++kt) wf[e][kt] = *FR(kt, e);
  // kt 6,7 -> LDS
#pragma unroll
  for (int e = 0; e < 3; ++e)
#pragma unroll
    for (int kt = 6; kt < 8; ++kt) *(short8*)&wlds[kt - 6][w][e][lane][0] = *FR(kt, e);

  float bh[3];
#pragma unroll
  for (int e = 0; e < 3; ++e) bh[e] = bhh[e * 256 + w * 16 + l15];

  for (int i = tid; i < 2 * 16 * 264; i += 1024) (&hl[0][0][0])[i] = 0;

  const int col = w * 16 + l15;
  const short* xpl = xp + ((long)(b0 + lhi) * 64) * 768 + col;

  float hreg = 0.f;
  short xc0 = xpl[0], xc1 = xpl[256], xc2 = xpl[512];  // prefetch xp[t=0]
  __syncthreads();  // weights/hl visible (full drain, once)

  for (int t = 0; t < 64; ++t) {
    const int cur = t & 1;
    const short* xpn = xpl + (long)(t + 1 < 64 ? t + 1 : 63) * 768;
    short xn0 = xpn[0], xn1 = xpn[256], xn2 = xpn[512];
    short8 s50 = *FR(5, 0), s51 = *FR(5, 1), s52 = *FR(5, 2);

    f32x4 acc[3];
#pragma unroll
    for (int e = 0; e < 3; ++e) acc[e] = (f32x4){0.f, 0.f, 0.f, 0.f};
#pragma unroll
    for (int kt = 0; kt < 5; ++kt) {
      short8 a = *(const short8*)&hl[cur][l15][kt * 32 + lhi * 8];
      acc[0] = __builtin_amdgcn_mfma_f32_16x16x32_bf16(a, wf[0][kt], acc[0], 0, 0, 0);
      acc[1] = __builtin_amdgcn_mfma_f32_16x16x32_bf16(a, wf[1][kt], acc[1], 0, 0, 0);
      acc[2] = __builtin_amdgcn_mfma_f32_16x16x32_bf16(a, wf[2][kt], acc[2], 0, 0, 0);
    }
    {
      short8 a = *(const short8*)&hl[cur][l15][5 * 32 + lhi * 8];
      acc[0] = __builtin_amdgcn_mfma_f32_16x16x32_bf16(a, s50, acc[0], 0, 0, 0);
      acc[1] = __builtin_amdgcn_mfma_f32_16x16x32_bf16(a, s51, acc[1], 0, 0, 0);
      acc[2] = __builtin_amdgcn_mfma_f32_16x16x32_bf16(a, s52, acc[2], 0, 0, 0);
    }
#pragma unroll
    for (int kt = 6; kt < 8; ++kt) {
      short8 a = *(const short8*)&hl[cur][l15][kt * 32 + lhi * 8];
#pragma unroll
      for (int e = 0; e < 3; ++e) {
        short8 wl = *(const short8*)&wlds[kt - 6][w][e][lane][0];
        acc[e] = __builtin_amdgcn_mfma_f32_16x16x32_bf16(a, wl, acc[e], 0, 0, 0);
      }
    }

    {
      const float r = sigf(bf2f(xc0) + acc[0][0] + bh[0]);
      const float z = sigf(bf2f(xc1) + acc[1][0] + bh[1]);
      const float n = tanh_fast(bf2f(xc2) + r * (acc[2][0] + bh[2]));
      const float hn = (1.f - z) * n + z * hreg;
      hreg = hn;
      const short hb = f2bf(hn);
      hl[cur ^ 1][lhi << 2][col] = hb;
      outp[((long)(b0 + lhi) * 64 + t) * 256 + col] = hb;
    }
    xc0 = xn0; xc1 = xn1; xc2 = xn2;
    asm volatile("s_waitcnt lgkmcnt(0)" ::: "memory");
    __builtin_amdgcn_sched_barrier(0);
    __builtin_amdgcn_s_barrier();
    __builtin_amdgcn_sched_barrier(0);
  }
}

// ---------------- fused e_alpha softmax + context + combined (bf16 inputs) ----------------
__global__ __launch_bounds__(256) void alpha_ctx(const short* __restrict__ aout16,
                                                 const float* __restrict__ aW,
                                                 const float* __restrict__ ab,
                                                 const short* __restrict__ emb16,
                                                 const short* __restrict__ beta16,
                                                 const float* __restrict__ demo,
                                                 float* __restrict__ comb) {
  __shared__ float part[64][4];
  __shared__ float al[64];
  const int b = blockIdx.x, tid = threadIdx.x;
  const int t = tid >> 2, q = tid & 3;
  const short* p = aout16 + (long)(b * 64 + t) * 256 + q * 64;
  const float* wv = aW + q * 64;
  float s = 0.f;
  for (int i = 0; i < 64; ++i) s += bf2f(p[i]) * wv[i];
  part[t][q] = s;
  __syncthreads();
  if (tid < 64) {
    float e = part[tid][0] + part[tid][1] + part[tid][2] + part[tid][3] + ab[0];
    float m = e;
    for (int k = 32; k; k >>= 1) m = fmaxf(m, __shfl_xor(m, k));
    float ex = __expf(e - m);
    float sum = ex;
    for (int k = 32; k; k >>= 1) sum += __shfl_xor(sum, k);
    al[tid] = ex / sum;
  }
  __syncthreads();
  const int h = tid;
  float acc = 0.f;
  for (int t2 = 0; t2 < 64; ++t2) {
    const long ix = (long)(b * 64 + t2) * 256 + h;
    acc += al[t2] * bf2f(emb16[ix]) * bf2f(beta16[ix]);
  }
  comb[b * 288 + h] = acc;
  if (h < 16) comb[b * 288 + 256 + h] = demo[b * 16 + h];
  else if (h < 32) comb[b * 288 + 256 + h] = 0.f;
}

// ---------------- death/LOS head final dot ----------------
__global__ __launch_bounds__(64) void dl_head(const float* __restrict__ h2,
                                              const float* __restrict__ w,
                                              const float* __restrict__ bias,
                                              float* __restrict__ out) {
  const int b = blockIdx.x, lane = threadIdx.x;
  float s = 0.f;
#pragma unroll
  for (int i = 0; i < 4; ++i) s += h2[b * 256 + lane * 4 + i] * w[lane * 4 + i];
  for (int k = 32; k; k >>= 1) s += __shfl_xor(s, k);
  if (lane == 0) out[(long)b * 8001 + 8000] = s + bias[0];
}

extern "C" void kernel_launch(void* const* d_in, const int* in_sizes, int n_in,
                              void* d_out, int out_size, void* d_ws, size_t ws_size,
                              hipStream_t stream) {
  (void)in_sizes; (void)n_in; (void)out_size; (void)ws_size;
  const float* x      = (const float*)d_in[0];
  const float* demo   = (const float*)d_in[1];
  const float* embW   = (const float*)d_in[2];
  const float* embB   = (const float*)d_in[3];
  const float* aWih   = (const float*)d_in[4];
  const float* aWhh   = (const float*)d_in[5];
  const float* abih   = (const float*)d_in[6];
  const float* abhh   = (const float*)d_in[7];
  const float* bWih   = (const float*)d_in[8];
  const float* bWhh   = (const float*)d_in[9];
  const float* bbih   = (const float*)d_in[10];
  const float* bbhh   = (const float*)d_in[11];
  const float* attnAW = (const float*)d_in[12];
  const float* attnAb = (const float*)d_in[13];
  const float* attnBW = (const float*)d_in[14];
  const float* attnBb = (const float*)d_in[15];
  const float* clsW1  = (const float*)d_in[16];
  const float* clsb1  = (const float*)d_in[17];
  const float* clsW2  = (const float*)d_in[18];
  const float* clsb2  = (const float*)d_in[19];
  const float* dlW1   = (const float*)d_in[20];
  const float* dlb1   = (const float*)d_in[21];
  const float* dlW2   = (const float*)d_in[22];
  const float* dlb2   = (const float*)d_in[23];
  float* out = (float*)d_out;
  float* ws = (float*)d_ws;

  short* Wt16    = (short*)ws;                // 2,048,000 s
  short* emb16   = Wt16 + 2048000;            // 2,097,152 s
  short* xpa16   = emb16 + 2097152;           // 6,291,456 s
  short* xpb16   = xpa16 + 6291456;           // 6,291,456 s
  short* aout16  = xpb16 + 6291456;           // 2,097,152 s
  short* bout16  = aout16 + 2097152;          // 2,097,152 s
  short* beta16  = bout16 + 2097152;          // 2,097,152 s
  float* comb    = (float*)(beta16 + 2097152); // 36,864 f
  float* h1      = comb + 36864;              // 32,768 f
  float* h2      = h1 + 32768;                // 32,768 f
  float* W1p     = h2 + 32768;                // 73,728 f
  float* W1pd    = W1p + 73728;               // 73,728 f
  short* wbf     = (short*)(W1pd + 73728);    // 393,216 s
  short* wih16a  = wbf + 393216;              // 196,608 s
  short* wih16b  = wih16a + 196608;           // 196,608 s
  short* attnBW16 = wih16b + 196608;          // 65,536 s

  prep<<<dim3(4560), dim3(256), 0, stream>>>(embW, Wt16, clsW1, dlW1, W1p, W1pd,
                                             aWhh, bWhh, wbf, aWih, bWih, attnBW,
                                             wih16a, wih16b, attnBW16);
  embed_sparse<<<dim3(8192), dim3(256), 0, stream>>>(x, Wt16, embB, emb16);
  gemm_dual16<<<dim3(12, 128), dim3(256), 0, stream>>>(emb16, wih16a, wih16b, abih, bbih,
                                                       xpa16, xpb16, 256);
  gru_scan<<<dim3(64), dim3(1024), 0, stream>>>(xpa16, xpb16, wbf, abhh, bbhh, aout16, bout16);
  gemm16_bt<<<dim3(4, 128), dim3(256), 0, stream>>>(bout16, attnBW16, attnBb, beta16, 256, 256);
  alpha_ctx<<<dim3(128), dim3(256), 0, stream>>>(aout16, attnAW, attnAb, emb16, beta16, demo, comb);
  gemm_heads<<<dim3(4, 2, 2), dim3(256), 0, stream>>>(comb, W1p, W1pd, clsb1, dlb1, h1, h2);
  gemm_bt<<<dim3(125, 2), dim3(256), 0, stream>>>(h1, clsW2, clsb2, out, 128, 8000, 256, 8001, 0);
  dl_head<<<dim3(128), dim3(64), 0, stream>>>(h2, dlW2, dlb2, out);
}